// Round 5
// baseline (55.283 us; speedup 1.0000x reference)
//
#include <hip/hip_runtime.h>
#include <math.h>

typedef float f4 __attribute__((ext_vector_type(4)));

struct F3 { float x, y, z; };

__device__ __forceinline__ F3 f3(float x, float y, float z) { return {x, y, z}; }
__device__ __forceinline__ F3 add(F3 a, F3 b) { return {a.x+b.x, a.y+b.y, a.z+b.z}; }
__device__ __forceinline__ F3 sub(F3 a, F3 b) { return {a.x-b.x, a.y-b.y, a.z-b.z}; }
__device__ __forceinline__ F3 mul(F3 a, float s) { return {a.x*s, a.y*s, a.z*s}; }
__device__ __forceinline__ float dot3(F3 a, F3 b) { return a.x*b.x + a.y*b.y + a.z*b.z; }
__device__ __forceinline__ F3 cross3(F3 a, F3 b) {
    return {a.y*b.z - a.z*b.y, a.z*b.x - a.x*b.z, a.x*b.y - a.y*b.x};
}
__device__ __forceinline__ F3 safe_normalize(F3 a) {
    float d = dot3(a, a);
    float inv = rsqrtf(fmaxf(d, 1e-20f));
    return mul(a, inv);
}

#define BLK 256

// ---------------------------------------------------------------------------
// Kernel 1: per-face geometry -> 32B record (2 x float4), quaternion-coded
//   tab[2f+0] = {fc.x, fc.y, fc.z, fs}
//   tab[2f+1] = {qw, qx, qy, qz}   with R(q) = [a0 | a1 | a2]
// ---------------------------------------------------------------------------
__global__ __launch_bounds__(BLK) void face_precompute_kernel(
    const float* __restrict__ verts, const int* __restrict__ faces,
    f4* __restrict__ tab, int F)
{
    const int f = blockIdx.x * BLK + threadIdx.x;
    if (f >= F) return;
    const int f0 = faces[3*f+0], f1 = faces[3*f+1], f2 = faces[3*f+2];
    const F3 v0 = f3(verts[3*f0], verts[3*f0+1], verts[3*f0+2]);
    const F3 v1 = f3(verts[3*f1], verts[3*f1+1], verts[3*f1+2]);
    const F3 v2 = f3(verts[3*f2], verts[3*f2+1], verts[3*f2+2]);

    const F3 fc  = mul(add(add(v0, v1), v2), (1.0f/3.0f));
    const F3 e01 = sub(v1, v0);
    const F3 e02 = sub(v2, v0);
    const F3 a0 = safe_normalize(e01);
    const F3 a1 = safe_normalize(cross3(a0, e02));
    const F3 a2 = mul(safe_normalize(cross3(a1, a0)), -1.0f);
    const float s0 = sqrtf(dot3(e01, e01));
    const float s1 = fabsf(dot3(a2, e02));
    const float fs = 0.5f * (s0 + s1);

    // rotation matrix with columns a0,a1,a2 -> quaternion (w,x,y,z)
    const float R00 = a0.x, R10 = a0.y, R20 = a0.z;
    const float R01 = a1.x, R11 = a1.y, R21 = a1.z;
    const float R02 = a2.x, R12 = a2.y, R22 = a2.z;
    float qw, qx, qy, qz;
    const float tr = R00 + R11 + R22;
    if (tr > 0.0f) {
        const float s = 0.5f / sqrtf(tr + 1.0f);
        qw = 0.25f / s;
        qx = (R21 - R12) * s;
        qy = (R02 - R20) * s;
        qz = (R10 - R01) * s;
    } else if (R00 > R11 && R00 > R22) {
        const float s = 2.0f * sqrtf(1.0f + R00 - R11 - R22);
        qw = (R21 - R12) / s;
        qx = 0.25f * s;
        qy = (R01 + R10) / s;
        qz = (R02 + R20) / s;
    } else if (R11 > R22) {
        const float s = 2.0f * sqrtf(1.0f + R11 - R00 - R22);
        qw = (R02 - R20) / s;
        qx = (R01 + R10) / s;
        qy = 0.25f * s;
        qz = (R12 + R21) / s;
    } else {
        const float s = 2.0f * sqrtf(1.0f + R22 - R00 - R11);
        qw = (R10 - R01) / s;
        qx = (R02 + R20) / s;
        qy = (R12 + R21) / s;
        qz = 0.25f * s;
    }
    const float qn = rsqrtf(fmaxf(qw*qw + qx*qx + qy*qy + qz*qz, 1e-30f));
    qw *= qn; qx *= qn; qy *= qn; qz *= qn;

    f4 r0; r0.x = fc.x; r0.y = fc.y; r0.z = fc.z; r0.w = fs;
    f4 r1; r1.x = qw;   r1.y = qx;   r1.z = qy;   r1.w = qz;
    tab[2*f+0] = r0;
    tab[2*f+1] = r1;
}

// ---------------------------------------------------------------------------
// Kernel 2: 1 point/thread. Streaming I/O is non-temporal (keeps L2 clean for
// the 325KB face table); stride-3 inputs staged via LDS as float4; output
// staged via LDS, flushed as nt float4.
// ---------------------------------------------------------------------------
__global__ __launch_bounds__(BLK) void gauss_main_kernel(
    const f4*    __restrict__ tab,       // (F,2) f4
    const int*   __restrict__ binding,   // (N,)
    const float* __restrict__ xyz,       // (N,3)
    const float* __restrict__ rot,       // (N,4)
    const float* __restrict__ scal,      // (N,3)
    const float* __restrict__ opac,      // (N,1)
    const float* __restrict__ fdc,       // (N,1,3)
    float*       __restrict__ out,       // (N,13)
    int N)
{
    __shared__ float sin_[3 * BLK * 3];   // [xyz | scal | fdc], 768 floats each
    __shared__ float sout[BLK * 13];

    const int tid  = threadIdx.x;
    const int base = blockIdx.x * BLK;
    const int i    = base + tid;
    const int count = min(BLK, N - base);
    const bool full = (count == BLK);

    // gather-chain root first
    const int b = (i < N) ? __builtin_nontemporal_load(binding + i) : 0;

    // face record gather (cached loads — table should live in L2)
    f4 t0 = {0,0,0,0}, t1 = {0,0,0,1};
    f4 q4 = {0,0,0,1};
    float opa = 0.0f;
    if (i < N) {
        t0 = tab[2*b+0];
        t1 = tab[2*b+1];
        q4 = __builtin_nontemporal_load(reinterpret_cast<const f4*>(rot) + i);
        opa = __builtin_nontemporal_load(opac + i);
    }

    if (full) {
        const f4* x4 = reinterpret_cast<const f4*>(xyz  + (size_t)base * 3);
        const f4* s4 = reinterpret_cast<const f4*>(scal + (size_t)base * 3);
        const f4* d4 = reinterpret_cast<const f4*>(fdc  + (size_t)base * 3);
        f4* sv = reinterpret_cast<f4*>(sin_);
        if (tid < 192) {               // 192 f4 per array
            sv[      tid] = __builtin_nontemporal_load(x4 + tid);
            sv[192 + tid] = __builtin_nontemporal_load(s4 + tid);
            sv[384 + tid] = __builtin_nontemporal_load(d4 + tid);
        }
    }

    float px, py, pz, sc0, sc1, sc2, d0, d1, d2;
    if (full) {
        __syncthreads();
        px  = sin_[        3*tid    ]; py  = sin_[        3*tid + 1]; pz  = sin_[        3*tid + 2];
        sc0 = sin_[ 768 +  3*tid    ]; sc1 = sin_[ 768 +  3*tid + 1]; sc2 = sin_[ 768 +  3*tid + 2];
        d0  = sin_[1536 +  3*tid    ]; d1  = sin_[1536 +  3*tid + 1]; d2  = sin_[1536 +  3*tid + 2];
    } else {
        px = py = pz = sc0 = sc1 = sc2 = d0 = d1 = d2 = 0.0f;
        if (i < N) {
            px  = xyz [3*i]; py  = xyz [3*i+1]; pz  = xyz [3*i+2];
            sc0 = scal[3*i]; sc1 = scal[3*i+1]; sc2 = scal[3*i+2];
            d0  = fdc [3*i]; d1  = fdc [3*i+1]; d2  = fdc [3*i+2];
        }
    }

    if (i < N) {
        const F3 fc = f3(t0.x, t0.y, t0.z);
        const float fs = t0.w;
        const float fw = t1.x, fx = t1.y, fy = t1.z, fz = t1.w;

        // xyz_out = (R(qf) * p) * fs + fc ; rotate via v = p + qw*t + qv x t
        const F3 p = f3(px, py, pz);
        const F3 qv = f3(fx, fy, fz);
        const F3 tt = mul(cross3(qv, p), 2.0f);
        const F3 v  = add(add(p, mul(tt, fw)), cross3(qv, tt));
        const F3 xo = add(mul(v, fs), fc);

        // normalize point quaternion (reference: q / (|q| + 1e-12))
        const float qn = sqrtf(q4.x*q4.x + q4.y*q4.y + q4.z*q4.z + q4.w*q4.w) + 1e-12f;
        const float qi = 1.0f / qn;
        const float pw = q4.x*qi, pxq = q4.y*qi, pyq = q4.z*qi, pzq = q4.w*qi;

        // compose qt = qf (Hamilton) qp  ->  R(qt) = O * Q
        const float tw = fw*pw  - fx*pxq - fy*pyq - fz*pzq;
        const float tx = fw*pxq + fx*pw  + fy*pzq - fz*pyq;
        const float ty = fw*pyq - fx*pzq + fy*pw  + fz*pxq;
        const float tz = fw*pzq + fx*pyq - fy*pxq + fz*pw;

        // M columns from qt
        const F3 m0 = f3(1.0f - 2.0f*(ty*ty + tz*tz),
                         2.0f*(tx*ty + tz*tw),
                         2.0f*(tx*tz - ty*tw));
        const F3 m1 = f3(2.0f*(tx*ty - tz*tw),
                         1.0f - 2.0f*(tx*tx + tz*tz),
                         2.0f*(ty*tz + tx*tw));
        const F3 m2 = f3(2.0f*(tx*tz + ty*tw),
                         2.0f*(ty*tz - tx*tw),
                         1.0f - 2.0f*(tx*tx + ty*ty));

        const float w0 = __expf(sc0) * fs;
        const float w1 = __expf(sc1) * fs;
        const float w2 = __expf(sc2) * fs;
        const float t0s = w0*w0, t1s = w1*w1, t2s = w2*w2;

        const float C00 = t0s*m0.x*m0.x + t1s*m1.x*m1.x + t2s*m2.x*m2.x;
        const float C01 = t0s*m0.x*m0.y + t1s*m1.x*m1.y + t2s*m2.x*m2.y;
        const float C02 = t0s*m0.x*m0.z + t1s*m1.x*m1.z + t2s*m2.x*m2.z;
        const float C11 = t0s*m0.y*m0.y + t1s*m1.y*m1.y + t2s*m2.y*m2.y;
        const float C12 = t0s*m0.y*m0.z + t1s*m1.y*m1.z + t2s*m2.y*m2.z;
        const float C22 = t0s*m0.z*m0.z + t1s*m1.z*m1.z + t2s*m2.z*m2.z;

        const float sg = 1.0f / (1.0f + __expf(-opa));

        float* s = sout + tid * 13;
        s[0]  = xo.x; s[1] = xo.y; s[2] = xo.z;
        s[3]  = fminf(fmaxf((0.5f + 0.282f*d0) * 255.0f, 0.0f), 255.0f);
        s[4]  = fminf(fmaxf((0.5f + 0.282f*d1) * 255.0f, 0.0f), 255.0f);
        s[5]  = fminf(fmaxf((0.5f + 0.282f*d2) * 255.0f, 0.0f), 255.0f);
        s[6]  = fminf(fmaxf(sg * 255.0f, 0.0f), 255.0f);
        s[7]  = C00; s[8] = C01; s[9] = C02; s[10] = C11; s[11] = C12; s[12] = C22;
    }

    __syncthreads();

    // coalesced nt float4 flush of the block's contiguous output span
    const int total = count * 13;
    const size_t obase = (size_t)base * 13;
    const int n4 = total >> 2;
    const f4* sf = reinterpret_cast<const f4*>(sout);
    f4* o4 = reinterpret_cast<f4*>(out + obase);
    for (int j = tid; j < n4; j += BLK) __builtin_nontemporal_store(sf[j], o4 + j);
    for (int j = (n4 << 2) + tid; j < total; j += BLK) out[obase + j] = sout[j];
}

// ---------------------------------------------------------------------------
// Fallback: fully fused single kernel (only if ws_size too small)
// ---------------------------------------------------------------------------
__global__ __launch_bounds__(BLK) void gauss_fused_kernel(
    const float* __restrict__ verts, const int* __restrict__ faces,
    const int* __restrict__ binding, const float* __restrict__ xyz,
    const float* __restrict__ rot, const float* __restrict__ scal,
    const float* __restrict__ opac, const float* __restrict__ fdc,
    float* __restrict__ out, int N)
{
    const int i = blockIdx.x * BLK + threadIdx.x;
    if (i >= N) return;
    const int b = binding[i];
    const int f0 = faces[3*b+0], f1 = faces[3*b+1], f2 = faces[3*b+2];
    const F3 v0 = f3(verts[3*f0], verts[3*f0+1], verts[3*f0+2]);
    const F3 v1 = f3(verts[3*f1], verts[3*f1+1], verts[3*f1+2]);
    const F3 v2 = f3(verts[3*f2], verts[3*f2+1], verts[3*f2+2]);
    const F3 fc  = mul(add(add(v0, v1), v2), (1.0f/3.0f));
    const F3 e01 = sub(v1, v0);
    const F3 e02 = sub(v2, v0);
    const F3 a0 = safe_normalize(e01);
    const F3 a1 = safe_normalize(cross3(a0, e02));
    const float s0 = sqrtf(dot3(e01, e01));
    const F3 a2 = mul(safe_normalize(cross3(a1, a0)), -1.0f);
    const float s1 = fabsf(dot3(a2, e02));
    const float fs = 0.5f * (s0 + s1);

    const float px = xyz[3*i], py = xyz[3*i+1], pz = xyz[3*i+2];
    const float qw0 = rot[4*i], qx0 = rot[4*i+1], qy0 = rot[4*i+2], qz0 = rot[4*i+3];
    const float sc0 = scal[3*i], sc1 = scal[3*i+1], sc2 = scal[3*i+2];
    const float opa = opac[i];
    const float d0 = fdc[3*i], d1 = fdc[3*i+1], d2 = fdc[3*i+2];

    F3 xo = add(add(mul(a0, px), mul(a1, py)), mul(a2, pz));
    xo = add(mul(xo, fs), fc);

    const float qn = sqrtf(qw0*qw0 + qx0*qx0 + qy0*qy0 + qz0*qz0) + 1e-12f;
    const float qi = 1.0f / qn;
    const float w = qw0*qi, x = qx0*qi, y = qy0*qi, z = qz0*qi;
    const float Q00 = 1.0f - 2.0f*(y*y + z*z);
    const float Q01 = 2.0f*(x*y - z*w);
    const float Q02 = 2.0f*(x*z + y*w);
    const float Q10 = 2.0f*(x*y + z*w);
    const float Q11 = 1.0f - 2.0f*(x*x + z*z);
    const float Q12 = 2.0f*(y*z - x*w);
    const float Q20 = 2.0f*(x*z - y*w);
    const float Q21 = 2.0f*(y*z + x*w);
    const float Q22 = 1.0f - 2.0f*(x*x + y*y);

    const F3 m0 = add(add(mul(a0, Q00), mul(a1, Q10)), mul(a2, Q20));
    const F3 m1 = add(add(mul(a0, Q01), mul(a1, Q11)), mul(a2, Q21));
    const F3 m2 = add(add(mul(a0, Q02), mul(a1, Q12)), mul(a2, Q22));

    const float w0 = __expf(sc0) * fs;
    const float w1 = __expf(sc1) * fs;
    const float w2 = __expf(sc2) * fs;
    const float t0s = w0*w0, t1s = w1*w1, t2s = w2*w2;

    float* op = out + (size_t)i * 13;
    op[0] = xo.x; op[1] = xo.y; op[2] = xo.z;
    op[3] = fminf(fmaxf((0.5f + 0.282f*d0) * 255.0f, 0.0f), 255.0f);
    op[4] = fminf(fmaxf((0.5f + 0.282f*d1) * 255.0f, 0.0f), 255.0f);
    op[5] = fminf(fmaxf((0.5f + 0.282f*d2) * 255.0f, 0.0f), 255.0f);
    op[6] = fminf(fmaxf((1.0f/(1.0f+__expf(-opa))) * 255.0f, 0.0f), 255.0f);
    op[7]  = t0s*m0.x*m0.x + t1s*m1.x*m1.x + t2s*m2.x*m2.x;
    op[8]  = t0s*m0.x*m0.y + t1s*m1.x*m1.y + t2s*m2.x*m2.y;
    op[9]  = t0s*m0.x*m0.z + t1s*m1.x*m1.z + t2s*m2.x*m2.z;
    op[10] = t0s*m0.y*m0.y + t1s*m1.y*m1.y + t2s*m2.y*m2.y;
    op[11] = t0s*m0.y*m0.z + t1s*m1.y*m1.z + t2s*m2.y*m2.z;
    op[12] = t0s*m0.z*m0.z + t1s*m1.z*m1.z + t2s*m2.z*m2.z;
}

extern "C" void kernel_launch(void* const* d_in, const int* in_sizes, int n_in,
                              void* d_out, int out_size, void* d_ws, size_t ws_size,
                              hipStream_t stream) {
    const float* verts   = (const float*)d_in[0];
    const int*   faces   = (const int*)  d_in[1];
    const int*   binding = (const int*)  d_in[2];
    const float* xyz     = (const float*)d_in[3];
    const float* rot     = (const float*)d_in[4];
    const float* scal    = (const float*)d_in[5];
    const float* opac    = (const float*)d_in[6];
    const float* fdc     = (const float*)d_in[7];
    // d_in[8] = features_rest: unused by the reference output
    float* out = (float*)d_out;
    const int N = in_sizes[2];
    const int F = in_sizes[1] / 3;

    const size_t tab_bytes = (size_t)F * 2 * sizeof(f4);
    const int blocks = (N + BLK - 1) / BLK;

    if (ws_size >= tab_bytes) {
        f4* tab = (f4*)d_ws;
        const int fblocks = (F + BLK - 1) / BLK;
        face_precompute_kernel<<<fblocks, BLK, 0, stream>>>(verts, faces, tab, F);
        gauss_main_kernel<<<blocks, BLK, 0, stream>>>(
            tab, binding, xyz, rot, scal, opac, fdc, out, N);
    } else {
        gauss_fused_kernel<<<blocks, BLK, 0, stream>>>(
            verts, faces, binding, xyz, rot, scal, opac, fdc, out, N);
    }
}

// Round 6
// 43.661 us; speedup vs baseline: 1.2662x; 1.2662x over previous
//
#include <hip/hip_runtime.h>
#include <math.h>

typedef float f4 __attribute__((ext_vector_type(4)));
typedef _Float16 h8 __attribute__((ext_vector_type(8)));

struct F3 { float x, y, z; };

__device__ __forceinline__ F3 f3(float x, float y, float z) { return {x, y, z}; }
__device__ __forceinline__ F3 add(F3 a, F3 b) { return {a.x+b.x, a.y+b.y, a.z+b.z}; }
__device__ __forceinline__ F3 sub(F3 a, F3 b) { return {a.x-b.x, a.y-b.y, a.z-b.z}; }
__device__ __forceinline__ F3 mul(F3 a, float s) { return {a.x*s, a.y*s, a.z*s}; }
__device__ __forceinline__ float dot3(F3 a, F3 b) { return a.x*b.x + a.y*b.y + a.z*b.z; }
__device__ __forceinline__ F3 cross3(F3 a, F3 b) {
    return {a.y*b.z - a.z*b.y, a.z*b.x - a.x*b.z, a.x*b.y - a.y*b.x};
}
__device__ __forceinline__ F3 safe_normalize(F3 a) {
    float d = dot3(a, a);
    float inv = rsqrtf(fmaxf(d, 1e-20f));
    return mul(a, inv);
}

#define BLK 256

// ---------------------------------------------------------------------------
// Kernel 1: per-face geometry -> ONE 16B record per face (8 x fp16):
//   { fc.x, fc.y, fc.z, fs, qw, qx, qy, qz }  with R(q) = [a0 | a1 | a2]
// 159 KB total: stays resident in every XCD's L2. One dwordx4 gather/point.
// fp16 rounding error ~1e-3 relative, vs absmax threshold 5.1 -> negligible.
// ---------------------------------------------------------------------------
__global__ __launch_bounds__(BLK) void face_precompute_kernel(
    const float* __restrict__ verts, const int* __restrict__ faces,
    h8* __restrict__ tab, int F)
{
    const int f = blockIdx.x * BLK + threadIdx.x;
    if (f >= F) return;
    const int f0 = faces[3*f+0], f1 = faces[3*f+1], f2 = faces[3*f+2];
    const F3 v0 = f3(verts[3*f0], verts[3*f0+1], verts[3*f0+2]);
    const F3 v1 = f3(verts[3*f1], verts[3*f1+1], verts[3*f1+2]);
    const F3 v2 = f3(verts[3*f2], verts[3*f2+1], verts[3*f2+2]);

    const F3 fc  = mul(add(add(v0, v1), v2), (1.0f/3.0f));
    const F3 e01 = sub(v1, v0);
    const F3 e02 = sub(v2, v0);
    const F3 a0 = safe_normalize(e01);
    const F3 a1 = safe_normalize(cross3(a0, e02));
    const F3 a2 = mul(safe_normalize(cross3(a1, a0)), -1.0f);
    const float s0 = sqrtf(dot3(e01, e01));
    const float s1 = fabsf(dot3(a2, e02));
    const float fs = 0.5f * (s0 + s1);

    // rotation matrix with columns a0,a1,a2 -> quaternion (w,x,y,z)
    const float R00 = a0.x, R10 = a0.y, R20 = a0.z;
    const float R01 = a1.x, R11 = a1.y, R21 = a1.z;
    const float R02 = a2.x, R12 = a2.y, R22 = a2.z;
    float qw, qx, qy, qz;
    const float tr = R00 + R11 + R22;
    if (tr > 0.0f) {
        const float s = 0.5f / sqrtf(tr + 1.0f);
        qw = 0.25f / s;
        qx = (R21 - R12) * s;
        qy = (R02 - R20) * s;
        qz = (R10 - R01) * s;
    } else if (R00 > R11 && R00 > R22) {
        const float s = 2.0f * sqrtf(1.0f + R00 - R11 - R22);
        qw = (R21 - R12) / s;
        qx = 0.25f * s;
        qy = (R01 + R10) / s;
        qz = (R02 + R20) / s;
    } else if (R11 > R22) {
        const float s = 2.0f * sqrtf(1.0f + R11 - R00 - R22);
        qw = (R02 - R20) / s;
        qx = (R01 + R10) / s;
        qy = 0.25f * s;
        qz = (R12 + R21) / s;
    } else {
        const float s = 2.0f * sqrtf(1.0f + R22 - R00 - R11);
        qw = (R10 - R01) / s;
        qx = (R02 + R20) / s;
        qy = (R12 + R21) / s;
        qz = 0.25f * s;
    }
    const float qn = rsqrtf(fmaxf(qw*qw + qx*qx + qy*qy + qz*qz, 1e-30f));
    qw *= qn; qx *= qn; qy *= qn; qz *= qn;

    h8 rec;
    rec[0] = (_Float16)fc.x; rec[1] = (_Float16)fc.y;
    rec[2] = (_Float16)fc.z; rec[3] = (_Float16)fs;
    rec[4] = (_Float16)qw;   rec[5] = (_Float16)qx;
    rec[6] = (_Float16)qy;   rec[7] = (_Float16)qz;
    tab[f] = rec;
}

// ---------------------------------------------------------------------------
// Kernel 2: 1 point/thread; ONE 16B face gather; stride-3 inputs staged via
// LDS as float4; output staged via LDS, flushed as coalesced float4.
// All loads/stores plain cached (R5 showed NT hints regress).
// ---------------------------------------------------------------------------
__global__ __launch_bounds__(BLK) void gauss_main_kernel(
    const h8*    __restrict__ tab,       // (F,) 16B records
    const int*   __restrict__ binding,   // (N,)
    const float* __restrict__ xyz,       // (N,3)
    const float* __restrict__ rot,       // (N,4)
    const float* __restrict__ scal,      // (N,3)
    const float* __restrict__ opac,      // (N,1)
    const float* __restrict__ fdc,       // (N,1,3)
    float*       __restrict__ out,       // (N,13)
    int N)
{
    __shared__ float sin_[3 * BLK * 3];   // [xyz | scal | fdc], 768 floats each
    __shared__ float sout[BLK * 13];

    const int tid  = threadIdx.x;
    const int base = blockIdx.x * BLK;
    const int i    = base + tid;
    const int count = min(BLK, N - base);
    const bool full = (count == BLK);

    // gather-chain root first
    const int b = (i < N) ? binding[i] : 0;

    // the single face-record gather + per-point coalesced loads
    h8 rec = {0,0,0,0, (_Float16)1.0f,0,0,0};
    f4 q4 = {0,0,0,1};
    float opa = 0.0f;
    if (i < N) {
        rec = tab[b];
        q4  = reinterpret_cast<const f4*>(rot)[i];
        opa = opac[i];
    }

    if (full) {
        const f4* x4 = reinterpret_cast<const f4*>(xyz  + (size_t)base * 3);
        const f4* s4 = reinterpret_cast<const f4*>(scal + (size_t)base * 3);
        const f4* d4 = reinterpret_cast<const f4*>(fdc  + (size_t)base * 3);
        f4* sv = reinterpret_cast<f4*>(sin_);
        if (tid < 192) {               // 192 f4 per array
            sv[      tid] = x4[tid];
            sv[192 + tid] = s4[tid];
            sv[384 + tid] = d4[tid];
        }
    }

    float px, py, pz, sc0, sc1, sc2, d0, d1, d2;
    if (full) {
        __syncthreads();
        px  = sin_[        3*tid    ]; py  = sin_[        3*tid + 1]; pz  = sin_[        3*tid + 2];
        sc0 = sin_[ 768 +  3*tid    ]; sc1 = sin_[ 768 +  3*tid + 1]; sc2 = sin_[ 768 +  3*tid + 2];
        d0  = sin_[1536 +  3*tid    ]; d1  = sin_[1536 +  3*tid + 1]; d2  = sin_[1536 +  3*tid + 2];
    } else {
        px = py = pz = sc0 = sc1 = sc2 = d0 = d1 = d2 = 0.0f;
        if (i < N) {
            px  = xyz [3*i]; py  = xyz [3*i+1]; pz  = xyz [3*i+2];
            sc0 = scal[3*i]; sc1 = scal[3*i+1]; sc2 = scal[3*i+2];
            d0  = fdc [3*i]; d1  = fdc [3*i+1]; d2  = fdc [3*i+2];
        }
    }

    if (i < N) {
        const F3 fc = f3((float)rec[0], (float)rec[1], (float)rec[2]);
        const float fs = (float)rec[3];
        const float fw = (float)rec[4], fx = (float)rec[5];
        const float fy = (float)rec[6], fz = (float)rec[7];

        // xyz_out = (R(qf) * p) * fs + fc ;  v = p + qw*t + qv x t, t = 2 qv x p
        const F3 p  = f3(px, py, pz);
        const F3 qv = f3(fx, fy, fz);
        const F3 tt = mul(cross3(qv, p), 2.0f);
        const F3 v  = add(add(p, mul(tt, fw)), cross3(qv, tt));
        const F3 xo = add(mul(v, fs), fc);

        // normalize point quaternion (reference: q / (|q| + 1e-12))
        const float qn = sqrtf(q4.x*q4.x + q4.y*q4.y + q4.z*q4.z + q4.w*q4.w) + 1e-12f;
        const float qi = 1.0f / qn;
        const float pw = q4.x*qi, pxq = q4.y*qi, pyq = q4.z*qi, pzq = q4.w*qi;

        // compose qt = qf (Hamilton) qp  ->  R(qt) = O * Q
        const float tw = fw*pw  - fx*pxq - fy*pyq - fz*pzq;
        const float tx = fw*pxq + fx*pw  + fy*pzq - fz*pyq;
        const float ty = fw*pyq - fx*pzq + fy*pw  + fz*pxq;
        const float tz = fw*pzq + fx*pyq - fy*pxq + fz*pw;

        // M columns from qt
        const F3 m0 = f3(1.0f - 2.0f*(ty*ty + tz*tz),
                         2.0f*(tx*ty + tz*tw),
                         2.0f*(tx*tz - ty*tw));
        const F3 m1 = f3(2.0f*(tx*ty - tz*tw),
                         1.0f - 2.0f*(tx*tx + tz*tz),
                         2.0f*(ty*tz + tx*tw));
        const F3 m2 = f3(2.0f*(tx*tz + ty*tw),
                         2.0f*(ty*tz - tx*tw),
                         1.0f - 2.0f*(tx*tx + ty*ty));

        const float w0 = __expf(sc0) * fs;
        const float w1 = __expf(sc1) * fs;
        const float w2 = __expf(sc2) * fs;
        const float t0s = w0*w0, t1s = w1*w1, t2s = w2*w2;

        const float C00 = t0s*m0.x*m0.x + t1s*m1.x*m1.x + t2s*m2.x*m2.x;
        const float C01 = t0s*m0.x*m0.y + t1s*m1.x*m1.y + t2s*m2.x*m2.y;
        const float C02 = t0s*m0.x*m0.z + t1s*m1.x*m1.z + t2s*m2.x*m2.z;
        const float C11 = t0s*m0.y*m0.y + t1s*m1.y*m1.y + t2s*m2.y*m2.y;
        const float C12 = t0s*m0.y*m0.z + t1s*m1.y*m1.z + t2s*m2.y*m2.z;
        const float C22 = t0s*m0.z*m0.z + t1s*m1.z*m1.z + t2s*m2.z*m2.z;

        const float sg = 1.0f / (1.0f + __expf(-opa));

        float* s = sout + tid * 13;
        s[0]  = xo.x; s[1] = xo.y; s[2] = xo.z;
        s[3]  = fminf(fmaxf((0.5f + 0.282f*d0) * 255.0f, 0.0f), 255.0f);
        s[4]  = fminf(fmaxf((0.5f + 0.282f*d1) * 255.0f, 0.0f), 255.0f);
        s[5]  = fminf(fmaxf((0.5f + 0.282f*d2) * 255.0f, 0.0f), 255.0f);
        s[6]  = fminf(fmaxf(sg * 255.0f, 0.0f), 255.0f);
        s[7]  = C00; s[8] = C01; s[9] = C02; s[10] = C11; s[11] = C12; s[12] = C22;
    }

    __syncthreads();

    // coalesced float4 flush of the block's contiguous output span
    const int total = count * 13;
    const size_t obase = (size_t)base * 13;
    const int n4 = total >> 2;
    const f4* sf = reinterpret_cast<const f4*>(sout);
    f4* o4 = reinterpret_cast<f4*>(out + obase);
    for (int j = tid; j < n4; j += BLK) o4[j] = sf[j];
    for (int j = (n4 << 2) + tid; j < total; j += BLK) out[obase + j] = sout[j];
}

// ---------------------------------------------------------------------------
// Fallback: fully fused single kernel (only if ws_size too small)
// ---------------------------------------------------------------------------
__global__ __launch_bounds__(BLK) void gauss_fused_kernel(
    const float* __restrict__ verts, const int* __restrict__ faces,
    const int* __restrict__ binding, const float* __restrict__ xyz,
    const float* __restrict__ rot, const float* __restrict__ scal,
    const float* __restrict__ opac, const float* __restrict__ fdc,
    float* __restrict__ out, int N)
{
    const int i = blockIdx.x * BLK + threadIdx.x;
    if (i >= N) return;
    const int b = binding[i];
    const int f0 = faces[3*b+0], f1 = faces[3*b+1], f2 = faces[3*b+2];
    const F3 v0 = f3(verts[3*f0], verts[3*f0+1], verts[3*f0+2]);
    const F3 v1 = f3(verts[3*f1], verts[3*f1+1], verts[3*f1+2]);
    const F3 v2 = f3(verts[3*f2], verts[3*f2+1], verts[3*f2+2]);
    const F3 fc  = mul(add(add(v0, v1), v2), (1.0f/3.0f));
    const F3 e01 = sub(v1, v0);
    const F3 e02 = sub(v2, v0);
    const F3 a0 = safe_normalize(e01);
    const F3 a1 = safe_normalize(cross3(a0, e02));
    const float s0 = sqrtf(dot3(e01, e01));
    const F3 a2 = mul(safe_normalize(cross3(a1, a0)), -1.0f);
    const float s1 = fabsf(dot3(a2, e02));
    const float fs = 0.5f * (s0 + s1);

    const float px = xyz[3*i], py = xyz[3*i+1], pz = xyz[3*i+2];
    const float qw0 = rot[4*i], qx0 = rot[4*i+1], qy0 = rot[4*i+2], qz0 = rot[4*i+3];
    const float sc0 = scal[3*i], sc1 = scal[3*i+1], sc2 = scal[3*i+2];
    const float opa = opac[i];
    const float d0 = fdc[3*i], d1 = fdc[3*i+1], d2 = fdc[3*i+2];

    F3 xo = add(add(mul(a0, px), mul(a1, py)), mul(a2, pz));
    xo = add(mul(xo, fs), fc);

    const float qn = sqrtf(qw0*qw0 + qx0*qx0 + qy0*qy0 + qz0*qz0) + 1e-12f;
    const float qi = 1.0f / qn;
    const float w = qw0*qi, x = qx0*qi, y = qy0*qi, z = qz0*qi;
    const float Q00 = 1.0f - 2.0f*(y*y + z*z);
    const float Q01 = 2.0f*(x*y - z*w);
    const float Q02 = 2.0f*(x*z + y*w);
    const float Q10 = 2.0f*(x*y + z*w);
    const float Q11 = 1.0f - 2.0f*(x*x + z*z);
    const float Q12 = 2.0f*(y*z - x*w);
    const float Q20 = 2.0f*(x*z - y*w);
    const float Q21 = 2.0f*(y*z + x*w);
    const float Q22 = 1.0f - 2.0f*(x*x + y*y);

    const F3 m0 = add(add(mul(a0, Q00), mul(a1, Q10)), mul(a2, Q20));
    const F3 m1 = add(add(mul(a0, Q01), mul(a1, Q11)), mul(a2, Q21));
    const F3 m2 = add(add(mul(a0, Q02), mul(a1, Q12)), mul(a2, Q22));

    const float w0 = __expf(sc0) * fs;
    const float w1 = __expf(sc1) * fs;
    const float w2 = __expf(sc2) * fs;
    const float t0s = w0*w0, t1s = w1*w1, t2s = w2*w2;

    float* op = out + (size_t)i * 13;
    op[0] = xo.x; op[1] = xo.y; op[2] = xo.z;
    op[3] = fminf(fmaxf((0.5f + 0.282f*d0) * 255.0f, 0.0f), 255.0f);
    op[4] = fminf(fmaxf((0.5f + 0.282f*d1) * 255.0f, 0.0f), 255.0f);
    op[5] = fminf(fmaxf((0.5f + 0.282f*d2) * 255.0f, 0.0f), 255.0f);
    op[6] = fminf(fmaxf((1.0f/(1.0f+__expf(-opa))) * 255.0f, 0.0f), 255.0f);
    op[7]  = t0s*m0.x*m0.x + t1s*m1.x*m1.x + t2s*m2.x*m2.x;
    op[8]  = t0s*m0.x*m0.y + t1s*m1.x*m1.y + t2s*m2.x*m2.y;
    op[9]  = t0s*m0.x*m0.z + t1s*m1.x*m1.z + t2s*m2.x*m2.z;
    op[10] = t0s*m0.y*m0.y + t1s*m1.y*m1.y + t2s*m2.y*m2.y;
    op[11] = t0s*m0.y*m0.z + t1s*m1.y*m1.z + t2s*m2.y*m2.z;
    op[12] = t0s*m0.z*m0.z + t1s*m1.z*m1.z + t2s*m2.z*m2.z;
}

extern "C" void kernel_launch(void* const* d_in, const int* in_sizes, int n_in,
                              void* d_out, int out_size, void* d_ws, size_t ws_size,
                              hipStream_t stream) {
    const float* verts   = (const float*)d_in[0];
    const int*   faces   = (const int*)  d_in[1];
    const int*   binding = (const int*)  d_in[2];
    const float* xyz     = (const float*)d_in[3];
    const float* rot     = (const float*)d_in[4];
    const float* scal    = (const float*)d_in[5];
    const float* opac    = (const float*)d_in[6];
    const float* fdc     = (const float*)d_in[7];
    // d_in[8] = features_rest: unused by the reference output
    float* out = (float*)d_out;
    const int N = in_sizes[2];
    const int F = in_sizes[1] / 3;

    const size_t tab_bytes = (size_t)F * sizeof(h8);
    const int blocks = (N + BLK - 1) / BLK;

    if (ws_size >= tab_bytes) {
        h8* tab = (h8*)d_ws;
        const int fblocks = (F + BLK - 1) / BLK;
        face_precompute_kernel<<<fblocks, BLK, 0, stream>>>(verts, faces, tab, F);
        gauss_main_kernel<<<blocks, BLK, 0, stream>>>(
            tab, binding, xyz, rot, scal, opac, fdc, out, N);
    } else {
        gauss_fused_kernel<<<blocks, BLK, 0, stream>>>(
            verts, faces, binding, xyz, rot, scal, opac, fdc, out, N);
    }
}